// Round 1
// baseline (320.435 us; speedup 1.0000x reference)
//
#include <hip/hip_runtime.h>
#include <hip/hip_bf16.h>

#define BH   16
#define SEQ  2048
#define DH   64
#define TQ   32
#define TK   32
#define KPAD 72   // 64 + 8 bf16 pad -> row stride 144B (16B-aligned, 2-way banks)
#define VPAD 40   // 32 + 8 bf16 pad -> row stride 80B
#define PPAD 40
#define NEGF (-4294967295.0f)   // rounds to -2^32 in f32, same as reference fill

using f32x4 = __attribute__((ext_vector_type(4))) float;
using s16x8 = __attribute__((ext_vector_type(8))) short;

static __device__ __forceinline__ short f2bf(float x) {
  union { float f; unsigned u; } v; v.f = x;
  unsigned r = v.u + 0x7fffu + ((v.u >> 16) & 1u);   // RNE
  return (short)(r >> 16);
}

__global__ __launch_bounds__(256)
void mha_fused_kernel(const float* __restrict__ key,
                      const float* __restrict__ value,
                      const float* __restrict__ query,
                      const int*   __restrict__ mask,
                      const float* __restrict__ qmask,
                      float* __restrict__ out_res,
                      float* __restrict__ out_attn)
{
  __shared__ short Qs[TQ][KPAD];
  __shared__ short Ks[TK][KPAD];
  __shared__ short Vt[DH][VPAD];   // V transposed: [d][k]
  __shared__ short Ps[TQ][PPAD];   // P tile bf16: [q][k]
  __shared__ float mpart[2][TQ];
  __shared__ float lpart[2][TQ];
  __shared__ float mrow[TQ];
  __shared__ float rscale[TQ];

  const int tid  = threadIdx.x;
  const int lane = tid & 63;
  const int wave = tid >> 6;
  const int lr   = lane & 15;   // fragment row/col index
  const int g    = lane >> 4;   // k-group within fragment
  const int qh   = wave >> 1;   // q half (0/1)
  const int kh   = wave & 1;    // k half in QK / d half in PV
  const int b    = blockIdx.y;
  const int q0   = blockIdx.x * TQ;

  const int sr = tid >> 3;          // staging row 0..31
  const int sc = (tid & 7) * 8;     // staging col 0,8,..,56

  // ---- stage Q tile once (f32 -> bf16) ----
  {
    const float* src = query + ((size_t)(b * SEQ + q0 + sr)) * DH + sc;
    float4 f0 = *(const float4*)src;
    float4 f1 = *(const float4*)(src + 4);
    s16x8 t;
    t[0]=f2bf(f0.x); t[1]=f2bf(f0.y); t[2]=f2bf(f0.z); t[3]=f2bf(f0.w);
    t[4]=f2bf(f1.x); t[5]=f2bf(f1.y); t[6]=f2bf(f1.z); t[7]=f2bf(f1.w);
    *(s16x8*)&Qs[sr][sc] = t;
  }

  const size_t mbase = (size_t)b * SEQ * SEQ;

  float m_i[4], l_i[4];
  #pragma unroll
  for (int i = 0; i < 4; ++i) { m_i[i] = NEGF; l_i[i] = 0.f; }

  // ================= pass 1: online softmax stats =================
  for (int kt = 0; kt < SEQ / TK; ++kt) {
    const int k0 = kt * TK;
    __syncthreads();
    { // stage K tile
      const float* src = key + ((size_t)(b * SEQ + k0 + sr)) * DH + sc;
      float4 f0 = *(const float4*)src;
      float4 f1 = *(const float4*)(src + 4);
      s16x8 t;
      t[0]=f2bf(f0.x); t[1]=f2bf(f0.y); t[2]=f2bf(f0.z); t[3]=f2bf(f0.w);
      t[4]=f2bf(f1.x); t[5]=f2bf(f1.y); t[6]=f2bf(f1.z); t[7]=f2bf(f1.w);
      *(s16x8*)&Ks[sr][sc] = t;
    }
    __syncthreads();

    f32x4 acc = {0.f, 0.f, 0.f, 0.f};
    #pragma unroll
    for (int dsq = 0; dsq < 2; ++dsq) {
      s16x8 a  = *(const s16x8*)&Qs[qh * 16 + lr][dsq * 32 + g * 8];
      s16x8 bb = *(const s16x8*)&Ks[kh * 16 + lr][dsq * 32 + g * 8];
      acc = __builtin_amdgcn_mfma_f32_16x16x32_bf16(a, bb, acc, 0, 0, 0);
    }

    #pragma unroll
    for (int i = 0; i < 4; ++i) {
      const int qg = qh * 16 + g * 4 + i;          // local q row
      const int kg = k0 + kh * 16 + lr;            // global k col
      const bool mk = mask[mbase + (size_t)(q0 + qg) * SEQ + kg] != 0;
      float s = mk ? NEGF : acc[i] * 0.125f;
      float tm = s;
      #pragma unroll
      for (int off = 1; off < 16; off <<= 1) tm = fmaxf(tm, __shfl_xor(tm, off));
      const float mn = fmaxf(m_i[i], tm);
      float p = __expf(s - mn);
      #pragma unroll
      for (int off = 1; off < 16; off <<= 1) p += __shfl_xor(p, off);
      l_i[i] = l_i[i] * __expf(m_i[i] - mn) + p;
      m_i[i] = mn;
    }
  }

  // ---- combine the two k-halves ----
  __syncthreads();
  if (lr == 0) {
    #pragma unroll
    for (int i = 0; i < 4; ++i) {
      mpart[kh][qh * 16 + g * 4 + i] = m_i[i];
      lpart[kh][qh * 16 + g * 4 + i] = l_i[i];
    }
  }
  __syncthreads();
  if (tid < TQ) {
    const float m0 = mpart[0][tid], m1 = mpart[1][tid];
    const float mm = fmaxf(m0, m1);
    const float ll = lpart[0][tid] * __expf(m0 - mm)
                   + lpart[1][tid] * __expf(m1 - mm);
    mrow[tid]   = mm;
    rscale[tid] = qmask[b * SEQ + q0 + tid] / ll;
  }
  __syncthreads();

  float mq[4], rs[4];
  #pragma unroll
  for (int i = 0; i < 4; ++i) {
    mq[i] = mrow[qh * 16 + g * 4 + i];
    rs[i] = rscale[qh * 16 + g * 4 + i];
  }

  f32x4 oacc0 = {0.f, 0.f, 0.f, 0.f};
  f32x4 oacc1 = {0.f, 0.f, 0.f, 0.f};

  // ================= pass 2: attention write + PV =================
  for (int kt = 0; kt < SEQ / TK; ++kt) {
    const int k0 = kt * TK;
    __syncthreads();   // previous PV reads of Ks/Vt/Ps done
    { // stage K tile
      const float* src = key + ((size_t)(b * SEQ + k0 + sr)) * DH + sc;
      float4 f0 = *(const float4*)src;
      float4 f1 = *(const float4*)(src + 4);
      s16x8 t;
      t[0]=f2bf(f0.x); t[1]=f2bf(f0.y); t[2]=f2bf(f0.z); t[3]=f2bf(f0.w);
      t[4]=f2bf(f1.x); t[5]=f2bf(f1.y); t[6]=f2bf(f1.z); t[7]=f2bf(f1.w);
      *(s16x8*)&Ks[sr][sc] = t;
    }
    { // stage V tile transposed
      const float* src = value + ((size_t)(b * SEQ + k0 + sr)) * DH + sc;
      float4 f0 = *(const float4*)src;
      float4 f1 = *(const float4*)(src + 4);
      Vt[sc + 0][sr] = f2bf(f0.x); Vt[sc + 1][sr] = f2bf(f0.y);
      Vt[sc + 2][sr] = f2bf(f0.z); Vt[sc + 3][sr] = f2bf(f0.w);
      Vt[sc + 4][sr] = f2bf(f1.x); Vt[sc + 5][sr] = f2bf(f1.y);
      Vt[sc + 6][sr] = f2bf(f1.z); Vt[sc + 7][sr] = f2bf(f1.w);
    }
    __syncthreads();

    f32x4 acc = {0.f, 0.f, 0.f, 0.f};
    #pragma unroll
    for (int dsq = 0; dsq < 2; ++dsq) {
      s16x8 a  = *(const s16x8*)&Qs[qh * 16 + lr][dsq * 32 + g * 8];
      s16x8 bb = *(const s16x8*)&Ks[kh * 16 + lr][dsq * 32 + g * 8];
      acc = __builtin_amdgcn_mfma_f32_16x16x32_bf16(a, bb, acc, 0, 0, 0);
    }

    #pragma unroll
    for (int i = 0; i < 4; ++i) {
      const int qg = qh * 16 + g * 4 + i;
      const int kg = k0 + kh * 16 + lr;
      const bool mk = mask[mbase + (size_t)(q0 + qg) * SEQ + kg] != 0;
      const float s = mk ? NEGF : acc[i] * 0.125f;
      const float p = __expf(s - mq[i]) * rs[i];   // final attn value
      out_attn[mbase + (size_t)(q0 + qg) * SEQ + kg] = p;
      Ps[qg][kh * 16 + lr] = f2bf(p);
    }
    __syncthreads();   // Ps / Vt ready for PV

    // PV: wave (qh, kh) computes q-half qh, d-range kh*32..kh*32+31
    s16x8 ap = *(const s16x8*)&Ps[qh * 16 + lr][g * 8];
    {
      s16x8 bv0 = *(const s16x8*)&Vt[kh * 32 + 0  + lr][g * 8];
      oacc0 = __builtin_amdgcn_mfma_f32_16x16x32_bf16(ap, bv0, oacc0, 0, 0, 0);
      s16x8 bv1 = *(const s16x8*)&Vt[kh * 32 + 16 + lr][g * 8];
      oacc1 = __builtin_amdgcn_mfma_f32_16x16x32_bf16(ap, bv1, oacc1, 0, 0, 0);
    }
  }

  // ---- write result (already scaled by qmask/l) ----
  #pragma unroll
  for (int i = 0; i < 4; ++i) {
    const int q = qh * 16 + g * 4 + i;
    out_res[((size_t)(b * SEQ + q0 + q)) * DH + kh * 32 + 0  + lr] = oacc0[i];
    out_res[((size_t)(b * SEQ + q0 + q)) * DH + kh * 32 + 16 + lr] = oacc1[i];
  }
}

extern "C" void kernel_launch(void* const* d_in, const int* in_sizes, int n_in,
                              void* d_out, int out_size, void* d_ws, size_t ws_size,
                              hipStream_t stream) {
  const float* key   = (const float*)d_in[0];
  const float* value = (const float*)d_in[1];
  const float* query = (const float*)d_in[2];
  const int*   mask  = (const int*)d_in[3];
  const float* qmask = (const float*)d_in[4];

  float* out_res  = (float*)d_out;                       // [16,2048,64]
  float* out_attn = out_res + (size_t)BH * SEQ * DH;     // [16,2048,2048]

  dim3 grid(SEQ / TQ, BH);
  mha_fused_kernel<<<grid, dim3(256), 0, stream>>>(
      key, value, query, mask, qmask, out_res, out_attn);
}

// Round 2
// 300.294 us; speedup vs baseline: 1.0671x; 1.0671x over previous
//
#include <hip/hip_runtime.h>
#include <hip/hip_bf16.h>

#define BH    16
#define SEQ   2048
#define DH    64
#define TQ    16
#define TK    64
#define NT    (SEQ / TK)      // 32 k-tiles
#define SCOLS 2056            // strip row stride in shorts (2048 + 8 pad -> 4112 B, 16B-aligned)
#define KP    72              // K/V tile row stride in shorts (144 B, 16B-aligned, bank-spread)
#define MP    68              // mask tile row stride in shorts (136 B -> g-groups land on distinct banks)
#define MFIX  12.0f           // fixed softmax offset; exact since normalization divides it out

using f32x4 = __attribute__((ext_vector_type(4))) float;
using s16x8 = __attribute__((ext_vector_type(8))) short;
using s16x4 = __attribute__((ext_vector_type(4))) short;

static __device__ __forceinline__ short f2bf(float x) {
  __hip_bfloat16 h = __float2bfloat16(x);   // native v_cvt_pk_bf16_f32 (RNE)
  union { __hip_bfloat16 h; short s; } u; u.h = h; return u.s;
}
static __device__ __forceinline__ float bf2f(short s) {
  union { unsigned u; float f; } v;
  v.u = ((unsigned)(unsigned short)s) << 16;
  return v.f;
}

__global__ __launch_bounds__(256)
void mha_onepass_kernel(const float* __restrict__ key,
                        const float* __restrict__ value,
                        const float* __restrict__ query,
                        const int*   __restrict__ mask,
                        const float* __restrict__ qmask,
                        float* __restrict__ out_res,
                        float* __restrict__ out_attn)
{
  __shared__ short Pstrip[TQ][SCOLS];   // 65792 B: unnormalized P (bf16) for full row strip
  __shared__ short KV[TK][KP];          //  9216 B: K tile, then V^T tile (disjoint lifetimes)
  __shared__ short Ms[TQ][MP];          //  2176 B: mask tile
  __shared__ short Qs[TQ][KP];          //  2304 B
  __shared__ float lred[4][TQ];
  __shared__ float rsc[TQ];             // total ~79.8 KB -> 2 blocks/CU

  const int tid  = threadIdx.x;
  const int lane = tid & 63;
  const int w    = tid >> 6;     // wave 0..3
  const int lr   = lane & 15;
  const int g    = lane >> 4;
  const int b    = blockIdx.y;
  const int q0   = blockIdx.x * TQ;
  const size_t mbase = (size_t)b * SEQ * SEQ;

  // ---- stage Q tile once (16 x 64, f32 -> bf16) ----
  {
    const int r = tid >> 4, c = (tid & 15) * 4;
    float4 f = *(const float4*)(query + ((size_t)(b * SEQ + q0 + r)) * DH + c);
    s16x4 t4 = { f2bf(f.x), f2bf(f.y), f2bf(f.z), f2bf(f.w) };
    *(s16x4*)&Qs[r][c] = t4;
  }

  f32x4 oacc = {0.f, 0.f, 0.f, 0.f};   // O[q 16][d w*16..+15], unnormalized

  for (int kt = 0; kt < NT; ++kt) {
    const int k0 = kt * TK;

    // ---- stage K tile (64 x 64) + mask tile (16 x 64) ----
    {
      const int kr = tid >> 2;
      const float* src = key + ((size_t)(b * SEQ + k0 + kr)) * DH;
      #pragma unroll
      for (int li = 0; li < 4; ++li) {
        const int c = (tid & 3) * 4 + li * 16;   // 4 lanes cover 64B contiguously per li
        float4 f = *(const float4*)(src + c);
        s16x4 t4 = { f2bf(f.x), f2bf(f.y), f2bf(f.z), f2bf(f.w) };
        *(s16x4*)&KV[kr][c] = t4;
      }
    }
    {
      const int r = tid >> 4, c = (tid & 15) * 4;
      int4 m = *(const int4*)(mask + mbase + (size_t)(q0 + r) * SEQ + k0 + c);
      s16x4 t4 = { (short)m.x, (short)m.y, (short)m.z, (short)m.w };
      *(s16x4*)&Ms[r][c] = t4;
    }
    __syncthreads();   // (1) K, Ms visible

    // ---- QK^T: wave w computes k-cols [w*16, w*16+16) for all 16 q-rows ----
    f32x4 acc = {0.f, 0.f, 0.f, 0.f};
    #pragma unroll
    for (int ch = 0; ch < 2; ++ch) {
      s16x8 a  = *(const s16x8*)&Qs[lr][ch * 32 + g * 8];
      s16x8 bb = *(const s16x8*)&KV[w * 16 + lr][ch * 32 + g * 8];
      acc = __builtin_amdgcn_mfma_f32_16x16x32_bf16(a, bb, acc, 0, 0, 0);
    }
    #pragma unroll
    for (int i = 0; i < 4; ++i) {
      const int qg = g * 4 + i;          // C layout: row = (l>>4)*4+i, col = l&15
      const int kc = w * 16 + lr;
      const bool mk = Ms[qg][kc] != 0;
      const float p = mk ? 0.f : __expf(acc[i] * 0.125f - MFIX);
      Pstrip[qg][k0 + kc] = f2bf(p);
    }
    __syncthreads();   // (2) K reads + strip writes done

    // ---- stage V^T tile into KV: KV[d][k] ----
    {
      const int kr = tid >> 2;
      const float* src = value + ((size_t)(b * SEQ + k0 + kr)) * DH;
      #pragma unroll
      for (int li = 0; li < 4; ++li) {
        const int c = (tid & 3) * 4 + li * 16;
        float4 f = *(const float4*)(src + c);
        KV[c + 0][kr] = f2bf(f.x);
        KV[c + 1][kr] = f2bf(f.y);
        KV[c + 2][kr] = f2bf(f.z);
        KV[c + 3][kr] = f2bf(f.w);
      }
    }
    __syncthreads();   // (3) V^T visible

    // ---- PV: wave w computes d-cols [w*16, w*16+16) ----
    #pragma unroll
    for (int ch = 0; ch < 2; ++ch) {
      s16x8 ap = *(const s16x8*)&Pstrip[lr][k0 + ch * 32 + g * 8];
      s16x8 bv = *(const s16x8*)&KV[w * 16 + lr][ch * 32 + g * 8];
      oacc = __builtin_amdgcn_mfma_f32_16x16x32_bf16(ap, bv, oacc, 0, 0, 0);
    }
    __syncthreads();   // (4) V^T reads done before next K stage
  }

  // ---- l per row (sum of strip) ----
  {
    const int r = tid & 15, s0 = tid >> 4;   // row r, 128-col segment s0
    float acc_l = 0.f;
    #pragma unroll
    for (int i = 0; i < 16; ++i) {
      const int sub = (i + s0) & 15;         // rotate sub-offset: bank-spread across s0 groups
      s16x8 v = *(const s16x8*)&Pstrip[r][s0 * 128 + sub * 8];
      float ss = 0.f;
      #pragma unroll
      for (int j = 0; j < 8; ++j) ss += bf2f(v[j]);
      acc_l += ss;
    }
    acc_l += __shfl_xor(acc_l, 16);
    acc_l += __shfl_xor(acc_l, 32);
    if ((lane >> 4) == 0) lred[w][lane & 15] = acc_l;
  }
  __syncthreads();
  if (tid < TQ) {
    const float l = lred[0][tid] + lred[1][tid] + lred[2][tid] + lred[3][tid];
    rsc[tid] = qmask[b * SEQ + q0 + tid] / fmaxf(l, 1e-37f);
  }
  __syncthreads();

  // ---- write result: O * qmask/l ----
  #pragma unroll
  for (int i = 0; i < 4; ++i) {
    const int q = g * 4 + i;
    out_res[((size_t)(b * SEQ + q0 + q)) * DH + w * 16 + lr] = oacc[i] * rsc[q];
  }

  // ---- write attention: p' * qmask/l, fully coalesced float4 ----
  {
    const int r = tid >> 4, cc = tid & 15;
    const float rs = rsc[r];
    float* dst = out_attn + mbase + (size_t)(q0 + r) * SEQ;
    #pragma unroll
    for (int it = 0; it < 16; ++it) {
      const int col = it * 128 + cc * 8;
      s16x8 v = *(const s16x8*)&Pstrip[r][col];
      float4 o0 = { bf2f(v[0]) * rs, bf2f(v[1]) * rs, bf2f(v[2]) * rs, bf2f(v[3]) * rs };
      float4 o1 = { bf2f(v[4]) * rs, bf2f(v[5]) * rs, bf2f(v[6]) * rs, bf2f(v[7]) * rs };
      *(float4*)(dst + col)     = o0;
      *(float4*)(dst + col + 4) = o1;
    }
  }
}

extern "C" void kernel_launch(void* const* d_in, const int* in_sizes, int n_in,
                              void* d_out, int out_size, void* d_ws, size_t ws_size,
                              hipStream_t stream) {
  const float* key   = (const float*)d_in[0];
  const float* value = (const float*)d_in[1];
  const float* query = (const float*)d_in[2];
  const int*   mask  = (const int*)d_in[3];
  const float* qmask = (const float*)d_in[4];

  float* out_res  = (float*)d_out;                       // [16,2048,64]
  float* out_attn = out_res + (size_t)BH * SEQ * DH;     // [16,2048,2048]

  dim3 grid(SEQ / TQ, BH);
  mha_onepass_kernel<<<grid, dim3(256), 0, stream>>>(
      key, value, query, mask, qmask, out_res, out_attn);
}

// Round 3
// 294.361 us; speedup vs baseline: 1.0886x; 1.0202x over previous
//
#include <hip/hip_runtime.h>
#include <hip/hip_bf16.h>

#define BH    16
#define SEQ   2048
#define DH    64
#define TQ    16
#define TK    64
#define NT    (SEQ / TK)     // 32 k-tiles
#define KP    72             // LDS row stride in shorts (144 B: 16B-aligned, 2-way banks)
#define MFIX  12.0f          // fixed softmax offset (divides out in normalization)

using f32x4 = __attribute__((ext_vector_type(4))) float;
using s16x8 = __attribute__((ext_vector_type(8))) short;
using s16x4 = __attribute__((ext_vector_type(4))) short;

static __device__ __forceinline__ short f2bf(float x) {
  union { __hip_bfloat16 h; short s; } u; u.h = __float2bfloat16(x); return u.s;
}
static __device__ __forceinline__ float bf2f(unsigned short s) {
  union { unsigned u; float f; } v; v.u = ((unsigned)s) << 16; return v.f;
}

__global__ __launch_bounds__(256, 3)
void mha_regp_kernel(const float* __restrict__ key,
                     const float* __restrict__ value,
                     const float* __restrict__ query,
                     const int*   __restrict__ mask,
                     const float* __restrict__ qmask,
                     float* __restrict__ out_res,
                     float* __restrict__ out_attn)
{
  __shared__ short Ks[2][TK][KP];   // 18432 B  K tiles, double-buffered
  __shared__ short Vt[2][DH][KP];   // 18432 B  V^T tiles ([d][k]), double-buffered
  __shared__ short Ps[TQ][KP];      //  2304 B  P tile for PV A-fragment
  __shared__ short Qs[TQ][KP];      //  2304 B
  __shared__ float lred[4][TQ];
  __shared__ float rsc[TQ];         // total ~41.8 KB -> 3 blocks/CU

  const int tid  = threadIdx.x;
  const int lane = tid & 63;
  const int w    = tid >> 6;
  const int lr   = lane & 15;
  const int g    = lane >> 4;
  const int b    = blockIdx.y;
  const int q0   = blockIdx.x * TQ;
  const size_t mbase = (size_t)b * SEQ * SEQ;

  // staging coords
  const int kr  = tid >> 2;          // K row 0..63
  const int kc0 = (tid & 3) * 4;     // K col base (+ li*16)
  const int vkb = (tid & 15) * 4;    // V k-block base
  const int vdb = (tid >> 4) * 4;    // V d-block base

  const float* kbase = key   + (size_t)b * SEQ * DH;
  const float* vbase = value + (size_t)b * SEQ * DH;

  // ---- stage Q tile (16x64) ----
  {
    const int r = tid >> 4, c = (tid & 15) * 4;
    f32x4 f = *(const f32x4*)(query + ((size_t)(b * SEQ + q0 + r)) * DH + c);
    s16x4 t4 = { f2bf(f[0]), f2bf(f[1]), f2bf(f[2]), f2bf(f[3]) };
    *(s16x4*)&Qs[r][c] = t4;
  }

  // ---- prefetch tile 0 into registers, then LDS buf 0 ----
  f32x4 kreg[4], vreg[4];
  int mreg[4];
  {
    const float* ks = kbase + (size_t)kr * DH;
    #pragma unroll
    for (int li = 0; li < 4; ++li) kreg[li] = *(const f32x4*)(ks + kc0 + li * 16);
    #pragma unroll
    for (int j = 0; j < 4; ++j)
      vreg[j] = *(const f32x4*)(vbase + (size_t)(vkb + j) * DH + vdb);
    #pragma unroll
    for (int i = 0; i < 4; ++i)
      mreg[i] = mask[mbase + (size_t)(q0 + g * 4 + i) * SEQ + w * 16 + lr];
  }
  #pragma unroll
  for (int li = 0; li < 4; ++li) {
    s16x4 t4 = { f2bf(kreg[li][0]), f2bf(kreg[li][1]), f2bf(kreg[li][2]), f2bf(kreg[li][3]) };
    *(s16x4*)&Ks[0][kr][kc0 + li * 16] = t4;
  }
  #pragma unroll
  for (int jj = 0; jj < 4; ++jj) {
    s16x4 t4 = { f2bf(vreg[0][jj]), f2bf(vreg[1][jj]), f2bf(vreg[2][jj]), f2bf(vreg[3][jj]) };
    *(s16x4*)&Vt[0][vdb + jj][vkb] = t4;
  }
  __syncthreads();

  // hoist Q fragments (Qs dead afterwards)
  const s16x8 qf0 = *(const s16x8*)&Qs[lr][g * 8];
  const s16x8 qf1 = *(const s16x8*)&Qs[lr][32 + g * 8];

  f32x4 oacc = {0.f, 0.f, 0.f, 0.f};
  float lacc[4] = {0.f, 0.f, 0.f, 0.f};
  unsigned P2[2 * NT];   // packed bf16 P, compile-time indexed (full unroll)

  #pragma unroll
  for (int kt = 0; kt < NT; ++kt) {
    const int cur = kt & 1, nxt = cur ^ 1;
    const int k0n = (kt + 1) * TK;

    // ---- issue prefetch for tile kt+1 (lands during this tile's compute) ----
    f32x4 kn[4], vn[4];
    int mn_[4];
    if (kt < NT - 1) {
      const float* ks = kbase + (size_t)(k0n + kr) * DH;
      #pragma unroll
      for (int li = 0; li < 4; ++li) kn[li] = *(const f32x4*)(ks + kc0 + li * 16);
      #pragma unroll
      for (int j = 0; j < 4; ++j)
        vn[j] = *(const f32x4*)(vbase + (size_t)(k0n + vkb + j) * DH + vdb);
      #pragma unroll
      for (int i = 0; i < 4; ++i)
        mn_[i] = mask[mbase + (size_t)(q0 + g * 4 + i) * SEQ + k0n + w * 16 + lr];
    }

    // ---- QK^T on buffer cur ----
    f32x4 acc = {0.f, 0.f, 0.f, 0.f};
    {
      s16x8 b0 = *(const s16x8*)&Ks[cur][w * 16 + lr][g * 8];
      acc = __builtin_amdgcn_mfma_f32_16x16x32_bf16(qf0, b0, acc, 0, 0, 0);
      s16x8 b1 = *(const s16x8*)&Ks[cur][w * 16 + lr][32 + g * 8];
      acc = __builtin_amdgcn_mfma_f32_16x16x32_bf16(qf1, b1, acc, 0, 0, 0);
    }

    // ---- mask + exp -> registers + Ps tile ----
    unsigned short ps[4];
    #pragma unroll
    for (int i = 0; i < 4; ++i) {
      const float p = mreg[i] ? 0.f : __expf(acc[i] * 0.125f - MFIX);
      lacc[i] += p;
      ps[i] = (unsigned short)f2bf(p);
      Ps[g * 4 + i][w * 16 + lr] = (short)ps[i];
    }
    P2[kt * 2 + 0] = (unsigned)ps[0] | ((unsigned)ps[1] << 16);
    P2[kt * 2 + 1] = (unsigned)ps[2] | ((unsigned)ps[3] << 16);
    if (kt < NT - 1) {
      #pragma unroll
      for (int i = 0; i < 4; ++i) mreg[i] = mn_[i];
    }
    __syncthreads();   // (1) Ps complete; Ks[cur] reads done

    // ---- PV on buffer cur ----
    {
      s16x8 a0 = *(const s16x8*)&Ps[lr][g * 8];
      s16x8 b0 = *(const s16x8*)&Vt[cur][w * 16 + lr][g * 8];
      oacc = __builtin_amdgcn_mfma_f32_16x16x32_bf16(a0, b0, oacc, 0, 0, 0);
      s16x8 a1 = *(const s16x8*)&Ps[lr][32 + g * 8];
      s16x8 b1 = *(const s16x8*)&Vt[cur][w * 16 + lr][32 + g * 8];
      oacc = __builtin_amdgcn_mfma_f32_16x16x32_bf16(a1, b1, oacc, 0, 0, 0);
    }

    // ---- write prefetched tile kt+1 into buffer nxt ----
    if (kt < NT - 1) {
      #pragma unroll
      for (int li = 0; li < 4; ++li) {
        s16x4 t4 = { f2bf(kn[li][0]), f2bf(kn[li][1]), f2bf(kn[li][2]), f2bf(kn[li][3]) };
        *(s16x4*)&Ks[nxt][kr][kc0 + li * 16] = t4;
      }
      #pragma unroll
      for (int jj = 0; jj < 4; ++jj) {
        s16x4 t4 = { f2bf(vn[0][jj]), f2bf(vn[1][jj]), f2bf(vn[2][jj]), f2bf(vn[3][jj]) };
        *(s16x4*)&Vt[nxt][vdb + jj][vkb] = t4;
      }
    }
    __syncthreads();   // (2) next buffers ready; Ps/Vt[cur] reads done
  }

  // ---- l per row: reduce lacc across the 16-lane lr group, then waves ----
  #pragma unroll
  for (int i = 0; i < 4; ++i) {
    float s = lacc[i];
    s += __shfl_xor(s, 1); s += __shfl_xor(s, 2);
    s += __shfl_xor(s, 4); s += __shfl_xor(s, 8);
    lacc[i] = s;
  }
  if (lr == 0) {
    #pragma unroll
    for (int i = 0; i < 4; ++i) lred[w][g * 4 + i] = lacc[i];
  }
  __syncthreads();
  if (tid < TQ) {
    const float l = lred[0][tid] + lred[1][tid] + lred[2][tid] + lred[3][tid];
    rsc[tid] = qmask[b * SEQ + q0 + tid] / fmaxf(l, 1e-37f);
  }
  __syncthreads();

  float rs[4];
  #pragma unroll
  for (int i = 0; i < 4; ++i) rs[i] = rsc[g * 4 + i];

  // ---- result write ----
  #pragma unroll
  for (int i = 0; i < 4; ++i)
    out_res[((size_t)(b * SEQ + q0 + g * 4 + i)) * DH + w * 16 + lr] = oacc[i] * rs[i];

  // ---- attention write from registers (64B/wave segments per store) ----
  float* arow = out_attn + mbase + (size_t)(q0 + g * 4) * SEQ + w * 16 + lr;
  #pragma unroll
  for (int kt = 0; kt < NT; ++kt) {
    #pragma unroll
    for (int i = 0; i < 4; ++i) {
      const unsigned u = P2[kt * 2 + (i >> 1)];
      const unsigned short h = (i & 1) ? (unsigned short)(u >> 16)
                                       : (unsigned short)(u & 0xffffu);
      arow[(size_t)i * SEQ + kt * 64] = bf2f(h) * rs[i];
    }
  }
}

extern "C" void kernel_launch(void* const* d_in, const int* in_sizes, int n_in,
                              void* d_out, int out_size, void* d_ws, size_t ws_size,
                              hipStream_t stream) {
  const float* key   = (const float*)d_in[0];
  const float* value = (const float*)d_in[1];
  const float* query = (const float*)d_in[2];
  const int*   mask  = (const int*)d_in[3];
  const float* qmask = (const float*)d_in[4];

  float* out_res  = (float*)d_out;                       // [16,2048,64]
  float* out_attn = out_res + (size_t)BH * SEQ * DH;     // [16,2048,2048]

  dim3 grid(SEQ / TQ, BH);
  mha_regp_kernel<<<grid, dim3(256), 0, stream>>>(
      key, value, query, mask, qmask, out_res, out_attn);
}